// Round 6
// baseline (2086.717 us; speedup 1.0000x reference)
//
#include <hip/hip_runtime.h>

// ============================================================================
// RetinaNetHead (S2ANet-style rotated head), MI355X gfx950.
// R6: h-halo A staging (stage once per (icq,dy), 3 dx taps read shifted rows,
//     boundary correctness via per-lane A-fragment zero masks) -> kills the
//     9x A HBM re-fetch (R5: FETCH 419MB vs x=67MB). + m204 bijective XCD
//     swizzle on m-blocks for L2 halo sharing.
// Conv = implicit GEMM, tiles: conv1 fused (128Mx128N, two B/acc banks),
// conv2 wide (128Mx256N). 2-barrier phases, global_load_lds(16B) staging,
// zero-page clamp for OOB rows. fp32 accum; logits/decode fp32.
//
// Workspace (ushort units):
//   [0)            feats NHWC fp16 (5 levels; region reused as conv2 output)
//   [44,695,552)   t1r fp16   [78,249,984) t1c fp16
//   [111,804,416)  conv weights fp16 4x[9][256][256]
//   [114,163,712)  wh [32][256]  [114,171,904) wc [64][256]
//   [114,188,288)  zp (64 zeros)
//   byte 228,376,704: hbuf fp32 [174592][24]   (total ~245.14 MB)
// ============================================================================

typedef __attribute__((ext_vector_type(8))) _Float16 f16x8;
typedef __attribute__((ext_vector_type(4))) float f32x4;

#define SCORES_TOTAL 10475520ull  // 8*87296*15

__device__ __forceinline__ unsigned short f2h(float f) {
  union { _Float16 h; unsigned short u; } x;
  x.h = (_Float16)f;
  return x.u;
}

__device__ __forceinline__ float sigmf(float x) {
  return 1.0f / (1.0f + expf(-x));
}

__device__ __forceinline__ void gload_lds16(const unsigned short* g,
                                            unsigned short* l) {
  __builtin_amdgcn_global_load_lds(
      (const __attribute__((address_space(1))) unsigned int*)g,
      (__attribute__((address_space(3))) unsigned int*)l, 16, 0, 0);
}

// m204 bijective XCD swizzle: consecutive remapped ids share an XCD.
__device__ __forceinline__ int xcd_swz(int bid, int nwg) {
  int q = nwg >> 3, r = nwg & 7;
  int x = bid & 7, i = bid >> 3;
  return (x < r ? x * (q + 1) : r * (q + 1) + (x - r) * q) + i;
}

// ---------------------------------------------------------------- weight prep
__global__ __launch_bounds__(256) void prep_convw(
    const float* __restrict__ w0, const float* __restrict__ w1,
    const float* __restrict__ w2, const float* __restrict__ w3,
    unsigned short* __restrict__ wtout) {
  int g = blockIdx.x * 256 + threadIdx.x;  // < 4*589824 = 2359296
  int q = g >> 16;            // 0..35
  int wsel = q / 9;
  int kk = q - wsel * 9;      // ky*3+kx
  int r = g & 65535;
  int oc = r >> 8, ic = r & 255;
  const float* src = (wsel == 0) ? w0 : (wsel == 1) ? w1 : (wsel == 2) ? w2 : w3;
  float v = src[(size_t)(oc * 256 + ic) * 9 + kk];  // OIHW flat
  wtout[(size_t)wsel * 589824 + (size_t)((kk << 8) + oc) * 256 + ic] = f2h(v);
}

__global__ __launch_bounds__(256) void prep_small(
    const float* __restrict__ clsh, const float* __restrict__ regh,
    const float* __restrict__ confw,
    unsigned short* __restrict__ wc, unsigned short* __restrict__ wh,
    unsigned short* __restrict__ zp) {
  int g = blockIdx.x * 256 + threadIdx.x;
  if (g < 16384) {
    int row = g >> 8, ic = g & 255;
    float v = (row < 60) ? clsh[row * 256 + ic] : 0.0f;
    wc[g] = f2h(v);
  } else if (g < 24576) {
    int gg = g - 16384;
    int row = gg >> 8, ic = gg & 255;
    float v = 0.0f;
    if (row < 20) v = regh[row * 256 + ic];
    else if (row < 24) v = confw[(row - 20) * 256 + ic];
    wh[gg] = f2h(v);
  } else if (g < 24640) {
    zp[g - 24576] = 0;
  }
}

// ---------------------------------------------------- NCHW fp32 -> NHWC fp16
__global__ __launch_bounds__(256) void to_nhwc(
    const float* __restrict__ in, unsigned short* __restrict__ out,
    int HW, int logHW) {
  __shared__ unsigned short L[64][258];
  const int t = threadIdx.x;
  const int b = blockIdx.y;
  const int hw0 = blockIdx.x * 64;
#pragma unroll
  for (int it = 0; it < 16; ++it) {
    int c = it * 16 + (t >> 4);
    int j4 = (t & 15) * 4;
    float4 v = *reinterpret_cast<const float4*>(
        in + (size_t)(b * 256 + c) * HW + hw0 + j4);
    L[j4 + 0][c] = f2h(v.x);
    L[j4 + 1][c] = f2h(v.y);
    L[j4 + 2][c] = f2h(v.z);
    L[j4 + 3][c] = f2h(v.w);
  }
  __syncthreads();
#pragma unroll
  for (int it = 0; it < 16; ++it) {
    int j = it * 4 + (t >> 6);
    int c4 = (t & 63) * 4;
    unsigned v0 = (unsigned)L[j][c4 + 0] | ((unsigned)L[j][c4 + 1] << 16);
    unsigned v1 = (unsigned)L[j][c4 + 2] | ((unsigned)L[j][c4 + 3] << 16);
    uint2 v = make_uint2(v0, v1);
    *reinterpret_cast<uint2*>(
        out + ((size_t)(b << logHW) + hw0 + j) * 256 + c4) = v;
  }
}

// --------------------------- conv1 both towers fused: 128Mx128N, halo-A
__global__ __launch_bounds__(256, 2) void conv3x3_fused2(
    const unsigned short* __restrict__ xin,   // [M][256] NHWC fp16
    const unsigned short* __restrict__ wtR,   // [9][256][256] fp16 (reg)
    const unsigned short* __restrict__ wtC,   // [9][256][256] fp16 (cls)
    const float* __restrict__ biasR, const float* __restrict__ biasC,
    const unsigned short* __restrict__ zp,
    unsigned short* __restrict__ outR, unsigned short* __restrict__ outC,
    int logW, int Mtot) {
  const int logHW = 2 * logW;
  const int H = 1 << logW, W = H;
  __shared__ unsigned short As[160 * 64];   // 20.5KB halo region (130 used)
  __shared__ unsigned short BlR[128 * 64];  // 16KB
  __shared__ unsigned short BlC[128 * 64];  // 16KB

  const int t = threadIdx.x;
  const int lane = t & 63;
  const int wv = t >> 6;
  const int wm = wv >> 1, wn = wv & 1;
  const int bid = xcd_swz(blockIdx.x, gridDim.x);
  const int m0 = bid * 128, n0 = blockIdx.y * 128;

  const int rsl = lane >> 3;
  const int chk = lane & 7;
  const unsigned short* bptrR[4];
  const unsigned short* bptrC[4];
  unsigned short* bldstR[4];
  unsigned short* bldstC[4];
#pragma unroll
  for (int i = 0; i < 4; ++i) {
    int slot = (wv << 2) + i;
    int row = n0 + (slot << 3) + rsl;
    bptrR[i] = wtR + ((size_t)row << 8) + (chk << 3);
    bptrC[i] = wtC + ((size_t)row << 8) + (chk << 3);
    bldstR[i] = BlR + (slot << 9);
    bldstC[i] = BlC + (slot << 9);
  }

  // per-mf boundary masks for this lane's A rows
  const int arow = (wm << 6) + (lane & 15);
  bool okw0[4], okw1[4], okh0[4], okh1[4];
#pragma unroll
  for (int mf = 0; mf < 4; ++mf) {
    int m = m0 + arow + (mf << 4);
    int wj = m & (W - 1);
    int hj = (m & ((1 << logHW) - 1)) >> logW;
    okw0[mf] = wj > 0;
    okw1[mf] = wj < W - 1;
    okh0[mf] = hj > 0;
    okh1[mf] = hj < H - 1;
  }

  f32x4 accR[4][4], accC[4][4];
#pragma unroll
  for (int i = 0; i < 4; ++i)
#pragma unroll
    for (int j = 0; j < 4; ++j) {
      accR[i][j] = (f32x4){0.f, 0.f, 0.f, 0.f};
      accC[i][j] = (f32x4){0.f, 0.f, 0.f, 0.f};
    }

  const int brow = (wn << 6) + (lane & 15);
  const int kb = ((lane >> 4) << 4);
  const f16x8 ZV = {(_Float16)0, (_Float16)0, (_Float16)0, (_Float16)0,
                    (_Float16)0, (_Float16)0, (_Float16)0, (_Float16)0};

#pragma unroll 1
  for (int icq = 0; icq < 4; ++icq) {
    const int ic0 = icq << 6;
#pragma unroll 1
    for (int dyi = 0; dyi < 3; ++dyi) {
      bool mdy[4];
#pragma unroll
      for (int mf = 0; mf < 4; ++mf)
        mdy[mf] = (dyi == 0) ? okh0[mf] : ((dyi == 2) ? okh1[mf] : true);
      const int grbase = m0 + (dyi - 1) * W - 1;
#pragma unroll
      for (int dxi = 0; dxi < 3; ++dxi) {
        __syncthreads();  // prior compute done before LDS overwrite
        if (dxi == 0) {   // stage A halo once per (icq,dy): rows grbase..+159
#pragma unroll
          for (int i = 0; i < 5; ++i) {
            int slot = t + (i << 8);
            int r = slot >> 3, chunk = slot & 7;
            int gr = grbase + r;
            const unsigned short* g = zp;
            if ((unsigned)gr < (unsigned)Mtot)
              g = xin + ((size_t)gr << 8) + ic0 + (chunk << 3);
            gload_lds16(g, As + slot * 8);
          }
        }
        const size_t bo = ((size_t)(dyi * 3 + dxi) << 16) + ic0;
#pragma unroll
        for (int i = 0; i < 4; ++i) gload_lds16(bptrR[i] + bo, bldstR[i]);
#pragma unroll
        for (int i = 0; i < 4; ++i) gload_lds16(bptrC[i] + bo, bldstC[i]);
        __syncthreads();  // vmcnt drain + barrier: tiles ready
#pragma unroll
        for (int ks = 0; ks < 2; ++ks) {
          f16x8 a[4], bR[4], bC[4];
#pragma unroll
          for (int mf = 0; mf < 4; ++mf) {
            a[mf] = *reinterpret_cast<const f16x8*>(
                (const char*)As + ((arow + (mf << 4) + dxi) << 7) + kb +
                (ks << 6));
            bool ok = mdy[mf] &&
                      (dxi == 0 ? okw0[mf] : (dxi == 2 ? okw1[mf] : true));
            if (!ok) a[mf] = ZV;
          }
#pragma unroll
          for (int nf = 0; nf < 4; ++nf) {
            bR[nf] = *reinterpret_cast<const f16x8*>(
                (const char*)BlR + ((brow + (nf << 4)) << 7) + kb + (ks << 6));
            bC[nf] = *reinterpret_cast<const f16x8*>(
                (const char*)BlC + ((brow + (nf << 4)) << 7) + kb + (ks << 6));
          }
#pragma unroll
          for (int mf = 0; mf < 4; ++mf)
#pragma unroll
            for (int nf = 0; nf < 4; ++nf) {
              accR[mf][nf] = __builtin_amdgcn_mfma_f32_16x16x32_f16(
                  a[mf], bR[nf], accR[mf][nf], 0, 0, 0);
              accC[mf][nf] = __builtin_amdgcn_mfma_f32_16x16x32_f16(
                  a[mf], bC[nf], accC[mf][nf], 0, 0, 0);
            }
        }
      }
    }
  }

  const int mrow0 = m0 + (wm << 6) + ((lane >> 4) << 2);
  const int ocol0 = n0 + (wn << 6) + (lane & 15);
#pragma unroll
  for (int nf = 0; nf < 4; ++nf) {
    int oc = ocol0 + (nf << 4);
    float biR = biasR[oc], biC = biasC[oc];
#pragma unroll
    for (int mf = 0; mf < 4; ++mf)
#pragma unroll
      for (int r = 0; r < 4; ++r) {
        int m = mrow0 + (mf << 4) + r;
        outR[((size_t)m << 8) + oc] = f2h(fmaxf(accR[mf][nf][r] + biR, 0.0f));
        outC[((size_t)m << 8) + oc] = f2h(fmaxf(accC[mf][nf][r] + biC, 0.0f));
      }
  }
}

// ----------------------------- conv2: 128Mx256N block, halo-A
__global__ __launch_bounds__(256, 2) void conv3x3_wide(
    const unsigned short* __restrict__ xin,  // [M][256] NHWC fp16
    const unsigned short* __restrict__ wt,   // [9][256][256] fp16
    const float* __restrict__ bias,          // [256]
    const unsigned short* __restrict__ zp,
    unsigned short* __restrict__ yout,       // [M][256] NHWC fp16
    int logW, int Mtot) {
  const int logHW = 2 * logW;
  const int H = 1 << logW, W = H;
  __shared__ unsigned short As[160 * 64];  // 20.5KB
  __shared__ unsigned short Bl[256 * 64];  // 32KB

  const int t = threadIdx.x;
  const int lane = t & 63;
  const int wv = t >> 6;
  const int wm = wv >> 1, wn = wv & 1;  // wave tile: 64M x 128N
  const int bid = xcd_swz(blockIdx.x, gridDim.x);
  const int m0 = bid * 128;

  const int rsl = lane >> 3;
  const int chk = lane & 7;
  const unsigned short* bptr[8];
  unsigned short* bldst[8];
#pragma unroll
  for (int i = 0; i < 8; ++i) {
    int slot = (wv << 3) + i;
    int row = (slot << 3) + rsl;
    bptr[i] = wt + ((size_t)row << 8) + (chk << 3);
    bldst[i] = Bl + (slot << 9);
  }

  const int arow = (wm << 6) + (lane & 15);
  bool okw0[4], okw1[4], okh0[4], okh1[4];
#pragma unroll
  for (int mf = 0; mf < 4; ++mf) {
    int m = m0 + arow + (mf << 4);
    int wj = m & (W - 1);
    int hj = (m & ((1 << logHW) - 1)) >> logW;
    okw0[mf] = wj > 0;
    okw1[mf] = wj < W - 1;
    okh0[mf] = hj > 0;
    okh1[mf] = hj < H - 1;
  }

  f32x4 acc[4][8];
#pragma unroll
  for (int i = 0; i < 4; ++i)
#pragma unroll
    for (int j = 0; j < 8; ++j) acc[i][j] = (f32x4){0.f, 0.f, 0.f, 0.f};

  const int brow = (wn << 7) + (lane & 15);
  const int kb = ((lane >> 4) << 4);
  const f16x8 ZV = {(_Float16)0, (_Float16)0, (_Float16)0, (_Float16)0,
                    (_Float16)0, (_Float16)0, (_Float16)0, (_Float16)0};

#pragma unroll 1
  for (int icq = 0; icq < 4; ++icq) {
    const int ic0 = icq << 6;
#pragma unroll 1
    for (int dyi = 0; dyi < 3; ++dyi) {
      bool mdy[4];
#pragma unroll
      for (int mf = 0; mf < 4; ++mf)
        mdy[mf] = (dyi == 0) ? okh0[mf] : ((dyi == 2) ? okh1[mf] : true);
      const int grbase = m0 + (dyi - 1) * W - 1;
#pragma unroll
      for (int dxi = 0; dxi < 3; ++dxi) {
        __syncthreads();
        if (dxi == 0) {
#pragma unroll
          for (int i = 0; i < 5; ++i) {
            int slot = t + (i << 8);
            int r = slot >> 3, chunk = slot & 7;
            int gr = grbase + r;
            const unsigned short* g = zp;
            if ((unsigned)gr < (unsigned)Mtot)
              g = xin + ((size_t)gr << 8) + ic0 + (chunk << 3);
            gload_lds16(g, As + slot * 8);
          }
        }
        const size_t bo = ((size_t)(dyi * 3 + dxi) << 16) + ic0;
#pragma unroll
        for (int i = 0; i < 8; ++i) gload_lds16(bptr[i] + bo, bldst[i]);
        __syncthreads();
#pragma unroll
        for (int ks = 0; ks < 2; ++ks) {
          f16x8 a[4], b[8];
#pragma unroll
          for (int mf = 0; mf < 4; ++mf) {
            a[mf] = *reinterpret_cast<const f16x8*>(
                (const char*)As + ((arow + (mf << 4) + dxi) << 7) + kb +
                (ks << 6));
            bool ok = mdy[mf] &&
                      (dxi == 0 ? okw0[mf] : (dxi == 2 ? okw1[mf] : true));
            if (!ok) a[mf] = ZV;
          }
#pragma unroll
          for (int nf = 0; nf < 8; ++nf)
            b[nf] = *reinterpret_cast<const f16x8*>(
                (const char*)Bl + ((brow + (nf << 4)) << 7) + kb + (ks << 6));
#pragma unroll
          for (int mf = 0; mf < 4; ++mf)
#pragma unroll
            for (int nf = 0; nf < 8; ++nf)
              acc[mf][nf] = __builtin_amdgcn_mfma_f32_16x16x32_f16(
                  a[mf], b[nf], acc[mf][nf], 0, 0, 0);
        }
      }
    }
  }

  const int mrow0 = m0 + (wm << 6) + ((lane >> 4) << 2);
  const int ocol0 = (wn << 7) + (lane & 15);
#pragma unroll
  for (int nf = 0; nf < 8; ++nf) {
    int oc = ocol0 + (nf << 4);
    float bi = bias[oc];
#pragma unroll
    for (int mf = 0; mf < 4; ++mf)
#pragma unroll
      for (int r = 0; r < 4; ++r) {
        int m = mrow0 + (mf << 4) + r;
        yout[((size_t)m << 8) + oc] = f2h(fmaxf(acc[mf][nf][r] + bi, 0.0f));
      }
  }
}

// -------------------------------------------- bbox(20)+conf(4) head -> hbuf
__global__ __launch_bounds__(256) void head24_mfma(
    const unsigned short* __restrict__ t2,  // [M][256] fp16
    const unsigned short* __restrict__ wh,  // [32][256] fp16 (24 valid)
    const float* __restrict__ regb, const float* __restrict__ confb,
    float* __restrict__ hbuf) {             // [M][24] fp32
  const int t = threadIdx.x, lane = t & 63, wv = t >> 6;
  const int rowb = blockIdx.x * 256 + wv * 64;
  const int kgrp = (lane >> 4) << 3;
  const int l15 = lane & 15;
  f32x4 acc[4][2];
#pragma unroll
  for (int i = 0; i < 4; ++i)
#pragma unroll
    for (int j = 0; j < 2; ++j) acc[i][j] = (f32x4){0.f, 0.f, 0.f, 0.f};
#pragma unroll
  for (int k0 = 0; k0 < 256; k0 += 32) {
    f16x8 a[4], b[2];
#pragma unroll
    for (int mf = 0; mf < 4; ++mf)
      a[mf] = *reinterpret_cast<const f16x8*>(
          t2 + (((size_t)(rowb + (mf << 4) + l15)) << 8) + k0 + kgrp);
#pragma unroll
    for (int nf = 0; nf < 2; ++nf)
      b[nf] = *reinterpret_cast<const f16x8*>(
          wh + (size_t)(((nf << 4) + l15) << 8) + k0 + kgrp);
#pragma unroll
    for (int mf = 0; mf < 4; ++mf)
#pragma unroll
      for (int nf = 0; nf < 2; ++nf)
        acc[mf][nf] = __builtin_amdgcn_mfma_f32_16x16x32_f16(
            a[mf], b[nf], acc[mf][nf], 0, 0, 0);
  }
#pragma unroll
  for (int nf = 0; nf < 2; ++nf) {
    int c = (nf << 4) + l15;
    if (c < 24) {
      float bi = (c < 20) ? regb[c] : confb[c - 20];
#pragma unroll
      for (int mf = 0; mf < 4; ++mf)
#pragma unroll
        for (int r = 0; r < 4; ++r) {
          int m = rowb + (mf << 4) + ((lane >> 4) << 2) + r;
          hbuf[(size_t)m * 24 + c] = acc[mf][nf][r] + bi;
        }
    }
  }
}

// ------------------------------------------- cls head + sigmoid*sigmoid out
__global__ __launch_bounds__(256) void cls_scores(
    const unsigned short* __restrict__ t2,  // [M][256] fp16
    const unsigned short* __restrict__ wc,  // [64][256] fp16 (60 valid)
    const float* __restrict__ clsb,
    const float* __restrict__ hbuf,         // [M][24] fp32 (conf at 20..23)
    float* __restrict__ outs,               // d_out scores base
    int logHW, int lvl_off) {
  const int t = threadIdx.x, lane = t & 63, wv = t >> 6;
  const int rowb = blockIdx.x * 256 + wv * 64;
  const int kgrp = (lane >> 4) << 3;
  const int l15 = lane & 15;
  const int HWm1 = (1 << logHW) - 1;
  f32x4 acc[4][4];
#pragma unroll
  for (int i = 0; i < 4; ++i)
#pragma unroll
    for (int j = 0; j < 4; ++j) acc[i][j] = (f32x4){0.f, 0.f, 0.f, 0.f};
#pragma unroll
  for (int k0 = 0; k0 < 256; k0 += 32) {
    f16x8 a[4], b[4];
#pragma unroll
    for (int mf = 0; mf < 4; ++mf)
      a[mf] = *reinterpret_cast<const f16x8*>(
          t2 + (((size_t)(rowb + (mf << 4) + l15)) << 8) + k0 + kgrp);
#pragma unroll
    for (int nf = 0; nf < 4; ++nf)
      b[nf] = *reinterpret_cast<const f16x8*>(
          wc + (size_t)(((nf << 4) + l15) << 8) + k0 + kgrp);
#pragma unroll
    for (int mf = 0; mf < 4; ++mf)
#pragma unroll
      for (int nf = 0; nf < 4; ++nf)
        acc[mf][nf] = __builtin_amdgcn_mfma_f32_16x16x32_f16(
            a[mf], b[nf], acc[mf][nf], 0, 0, 0);
  }
#pragma unroll
  for (int nf = 0; nf < 4; ++nf) {
    int c = (nf << 4) + l15;
    if (c < 60) {
      int ai = c / 15, ci = c - ai * 15;
      float bi = clsb[c];
#pragma unroll
      for (int mf = 0; mf < 4; ++mf)
#pragma unroll
        for (int r = 0; r < 4; ++r) {
          int m = rowb + (mf << 4) + ((lane >> 4) << 2) + r;
          float logit = acc[mf][nf][r] + bi;
          float conf = hbuf[(size_t)m * 24 + 20 + ai];
          float sc = sigmf(logit) * sigmf(conf);
          int b = m >> logHW;
          int hw = m & HWm1;
          int loc = lvl_off + (hw << 2) + ai;
          outs[(size_t)b * 1309440 + (size_t)loc * 15 + ci] = sc;
        }
    }
  }
}

// ------------------------------------------------------------- rbox decode
__global__ __launch_bounds__(256) void decode_k(
    const float* __restrict__ hbuf, float* __restrict__ outb,
    int logHW, int logW, int lvl_off, float stride, int total) {
  int tid = blockIdx.x * 256 + threadIdx.x;
  if (tid >= total) return;
  int m = tid >> 2, a = tid & 3;
  const float ANG[4] = {-0.39269908169872414f, 0.39269908169872414f,
                        1.1780972450961724f, 1.9634954084936207f};
  const float* d = hbuf + (size_t)m * 24 + a * 5;
  float dx = d[0], dy = d[1], dw = d[2], dh = d[3], da = d[4];
  int b = m >> logHW, hw = m & ((1 << logHW) - 1);
  int h = hw >> logW, w = hw & ((1 << logW) - 1);
  float ctr = 0.5f * (stride - 1.0f);
  float rx = w * stride + ctr, ry = h * stride + ctr;
  float rw = stride * 1.6329931618554521f;  // 4/sqrt(6)
  float rh = stride * 9.7979589711327124f;  // 4*sqrt(6)
  const float MR = 13.815510557964274f;     // |log(1e-6)|
  dw = fminf(fmaxf(dw, -MR), MR);
  dh = fminf(fmaxf(dh, -MR), MR);
  float gx = dx * rw + rx;
  float gy = dy * rh + ry;
  float gw = rw * expf(dw);
  float gh = rh * expf(dh);
  float v = da + ANG[a] + 0.7853981633974483f;
  float r = fmodf(v, 3.14159265358979323846f);
  if (r < 0.0f) r += 3.14159265358979323846f;
  float ga = r - 0.7853981633974483f;
  int loc = lvl_off + (hw << 2) + a;
  size_t base = (size_t)b * 436480 + (size_t)loc * 5;
  outb[base + 0] = gx;
  outb[base + 1] = gy;
  outb[base + 2] = gw;
  outb[base + 3] = gh;
  outb[base + 4] = ga;
}

// ============================================================================
extern "C" void kernel_launch(void* const* d_in, const int* in_sizes, int n_in,
                              void* d_out, int out_size, void* d_ws,
                              size_t ws_size, hipStream_t stream) {
  const float* feats[5];
  for (int i = 0; i < 5; ++i) feats[i] = (const float*)d_in[i];
  const float* reg_w0 = (const float*)d_in[5];
  const float* reg_b0 = (const float*)d_in[6];
  const float* reg_w1 = (const float*)d_in[7];
  const float* reg_b1 = (const float*)d_in[8];
  const float* cls_w0 = (const float*)d_in[9];
  const float* cls_b0 = (const float*)d_in[10];
  const float* cls_w1 = (const float*)d_in[11];
  const float* cls_b1 = (const float*)d_in[12];
  const float* reg_head_w = (const float*)d_in[13];
  const float* reg_head_b = (const float*)d_in[14];
  const float* cls_head_w = (const float*)d_in[15];
  const float* cls_head_b = (const float*)d_in[16];
  const float* conf_w = (const float*)d_in[17];
  const float* conf_b = (const float*)d_in[18];

  unsigned short* ws = (unsigned short*)d_ws;
  static const size_t xoff[5] = {0ull, 33554432ull, 41943040ull, 44040192ull,
                                 44564480ull};
  unsigned short* t1r = ws + 44695552ull;
  unsigned short* t1c = ws + 78249984ull;
  unsigned short* wt4 = ws + 111804416ull;
  unsigned short* wh = ws + 114163712ull;
  unsigned short* wc = ws + 114171904ull;
  unsigned short* zp = ws + 114188288ull;
  float* hbuf_all = (float*)((char*)d_ws + 228376704ull);

  prep_convw<<<9216, 256, 0, stream>>>(reg_w0, reg_w1, cls_w0, cls_w1, wt4);
  prep_small<<<97, 256, 0, stream>>>(cls_head_w, reg_head_w, conf_w, wc, wh,
                                     zp);

  static const int logWs[5] = {7, 6, 5, 4, 3};
  static const int lvl_off[5] = {0, 65536, 81920, 86016, 87040};
  static const int m_off[5] = {0, 131072, 163840, 172032, 174080};
  static const float strd[5] = {8.f, 16.f, 32.f, 64.f, 128.f};

  for (int l = 0; l < 5; ++l) {
    int HW = 1 << (2 * logWs[l]);
    to_nhwc<<<dim3(HW / 64, 8), 256, 0, stream>>>(feats[l], ws + xoff[l], HW,
                                                  2 * logWs[l]);
  }

  float* scores = (float*)d_out;
  float* boxes = (float*)d_out + SCORES_TOTAL;

  for (int l = 0; l < 5; ++l) {
    const int logW = logWs[l];
    const int HW = 1 << (2 * logW);
    const int M = 8 * HW;
    float* hb = hbuf_all + (size_t)m_off[l] * 24;
    unsigned short* x = ws + xoff[l];    // NHWC input; dead after conv1 -> t2
    unsigned short* t2 = x;              // conv2 output reuses x region

    conv3x3_fused2<<<dim3(M / 128, 2), 256, 0, stream>>>(
        x, wt4 + 0ull * 589824, wt4 + 2ull * 589824, reg_b0, cls_b0, zp, t1r,
        t1c, logW, M);
    conv3x3_wide<<<M / 128, 256, 0, stream>>>(t1r, wt4 + 1ull * 589824,
                                              reg_b1, zp, t2, logW, M);
    head24_mfma<<<M / 256, 256, 0, stream>>>(t2, wh, reg_head_b, conf_b, hb);
    conv3x3_wide<<<M / 128, 256, 0, stream>>>(t1c, wt4 + 3ull * 589824,
                                              cls_b1, zp, t2, logW, M);
    cls_scores<<<M / 256, 256, 0, stream>>>(t2, wc, cls_head_b, hb, scores,
                                            2 * logW, lvl_off[l]);
    decode_k<<<(M * 4 + 255) / 256, 256, 0, stream>>>(
        hb, boxes, 2 * logW, logW, lvl_off[l], strd[l], M * 4);
  }
}

// Round 7
// 1283.487 us; speedup vs baseline: 1.6258x; 1.6258x over previous
//
#include <hip/hip_runtime.h>

// ============================================================================
// RetinaNetHead (S2ANet-style rotated head), MI355X gfx950.
// R7: revert R6 halo (R5 per-tap staging was faster: stage+vmcnt+barrier is
//     the binding constraint, not HBM); vectorized epilogue via LDS transpose
//     (R5/R6 wrote 2B-scattered -> 1.5-2.4x HBM write amplification);
//     level-merged dispatches (L0 group + L1-4 group; to_nhwc/decode fully
//     merged) -> 30 -> 14 dispatches, kills small-level tail latency.
// Conv = implicit GEMM, conv1 fused (128Mx128N, two B/acc banks), conv2 wide
// (128Mx256N). 2-barrier phases, global_load_lds(16B), zero-page OOB clamp.
// fp32 accum; logits/decode fp32.
//
// Level geometry (hardcoded): rows gm 0..174591 concatenate levels
//   cum = {0,131072,163840,172032,174080,174592}, logW = {7,6,5,4,3}
// Workspace (ushort units), identical footprint to R3-R6 (~245.1MB):
//   [0)            feats NHWC fp16 all levels (reused as t2 after conv1)
//   [44,695,552)   t1r fp16 (per-group, reused L0 then L1-4)
//   [78,249,984)   t1c fp16
//   [111,804,416)  conv weights fp16 4x[9][256][256]
//   [114,163,712)  wh [32][256]  [114,171,904) wc [64][256]
//   [114,188,288)  zp (64 zeros)
//   byte 228,376,704: hbuf fp32 [174592][24]
// ============================================================================

typedef __attribute__((ext_vector_type(8))) _Float16 f16x8;
typedef __attribute__((ext_vector_type(4))) float f32x4;

#define SCORES_TOTAL 10475520ull  // 8*87296*15

__device__ __forceinline__ unsigned short f2h(float f) {
  union { _Float16 h; unsigned short u; } x;
  x.h = (_Float16)f;
  return x.u;
}

__device__ __forceinline__ float sigmf(float x) {
  return 1.0f / (1.0f + expf(-x));
}

__device__ __forceinline__ void gload_lds16(const unsigned short* g,
                                            unsigned short* l) {
  __builtin_amdgcn_global_load_lds(
      (const __attribute__((address_space(1))) unsigned int*)g,
      (__attribute__((address_space(3))) unsigned int*)l, 16, 0, 0);
}

// block-uniform level lookup from absolute row id
__device__ __forceinline__ void lvl_lookup(int gm, int& logW, int& mbase) {
  if (gm < 131072) { logW = 7; mbase = 0; }
  else if (gm < 163840) { logW = 6; mbase = 131072; }
  else if (gm < 172032) { logW = 5; mbase = 163840; }
  else if (gm < 174080) { logW = 4; mbase = 172032; }
  else { logW = 3; mbase = 174080; }
}

// ---------------------------------------------------------------- weight prep
__global__ __launch_bounds__(256) void prep_convw(
    const float* __restrict__ w0, const float* __restrict__ w1,
    const float* __restrict__ w2, const float* __restrict__ w3,
    unsigned short* __restrict__ wtout) {
  int g = blockIdx.x * 256 + threadIdx.x;  // < 4*589824
  int q = g >> 16;
  int wsel = q / 9;
  int kk = q - wsel * 9;
  int r = g & 65535;
  int oc = r >> 8, ic = r & 255;
  const float* src = (wsel == 0) ? w0 : (wsel == 1) ? w1 : (wsel == 2) ? w2 : w3;
  float v = src[(size_t)(oc * 256 + ic) * 9 + kk];
  wtout[(size_t)wsel * 589824 + (size_t)((kk << 8) + oc) * 256 + ic] = f2h(v);
}

__global__ __launch_bounds__(256) void prep_small(
    const float* __restrict__ clsh, const float* __restrict__ regh,
    const float* __restrict__ confw,
    unsigned short* __restrict__ wc, unsigned short* __restrict__ wh,
    unsigned short* __restrict__ zp) {
  int g = blockIdx.x * 256 + threadIdx.x;
  if (g < 16384) {
    int row = g >> 8, ic = g & 255;
    float v = (row < 60) ? clsh[row * 256 + ic] : 0.0f;
    wc[g] = f2h(v);
  } else if (g < 24576) {
    int gg = g - 16384;
    int row = gg >> 8, ic = gg & 255;
    float v = 0.0f;
    if (row < 20) v = regh[row * 256 + ic];
    else if (row < 24) v = confw[(row - 20) * 256 + ic];
    wh[gg] = f2h(v);
  } else if (g < 24640) {
    zp[g - 24576] = 0;
  }
}

// ------------------------------- NCHW fp32 -> NHWC fp16, all levels merged
__global__ __launch_bounds__(256) void to_nhwc_all(
    const float* __restrict__ f0, const float* __restrict__ f1,
    const float* __restrict__ f2, const float* __restrict__ f3,
    const float* __restrict__ f4, unsigned short* __restrict__ out) {
  __shared__ unsigned short L[64][258];
  const int t = threadIdx.x;
  const int gm0 = blockIdx.x * 64;
  int logW, mbase;
  const float* in;
  if (gm0 < 131072) { logW = 7; mbase = 0; in = f0; }
  else if (gm0 < 163840) { logW = 6; mbase = 131072; in = f1; }
  else if (gm0 < 172032) { logW = 5; mbase = 163840; in = f2; }
  else if (gm0 < 174080) { logW = 4; mbase = 172032; in = f3; }
  else { logW = 3; mbase = 174080; in = f4; }
  const int logHW = 2 * logW;
  const int HW = 1 << logHW;
  const int lm0 = gm0 - mbase;
  const int b = lm0 >> logHW;
  const int hw0 = lm0 & (HW - 1);
#pragma unroll
  for (int it = 0; it < 16; ++it) {
    int c = it * 16 + (t >> 4);
    int j4 = (t & 15) * 4;
    float4 v = *reinterpret_cast<const float4*>(
        in + (size_t)(b * 256 + c) * HW + hw0 + j4);
    L[j4 + 0][c] = f2h(v.x);
    L[j4 + 1][c] = f2h(v.y);
    L[j4 + 2][c] = f2h(v.z);
    L[j4 + 3][c] = f2h(v.w);
  }
  __syncthreads();
#pragma unroll
  for (int it = 0; it < 16; ++it) {
    int j = it * 4 + (t >> 6);
    int c4 = (t & 63) * 4;
    unsigned v0 = (unsigned)L[j][c4 + 0] | ((unsigned)L[j][c4 + 1] << 16);
    unsigned v1 = (unsigned)L[j][c4 + 2] | ((unsigned)L[j][c4 + 3] << 16);
    uint2 v = make_uint2(v0, v1);
    *reinterpret_cast<uint2*>(out + ((size_t)(gm0 + j) << 8) + c4) = v;
  }
}

// --------------------------- conv1 both towers fused: 128Mx128N, per-tap A
__global__ __launch_bounds__(256, 2) void conv1f(
    const unsigned short* __restrict__ xin,   // absolute rows [gm][256]
    const unsigned short* __restrict__ wtR,
    const unsigned short* __restrict__ wtC,
    const float* __restrict__ biasR, const float* __restrict__ biasC,
    const unsigned short* __restrict__ zp,
    unsigned short* __restrict__ outR,        // group-local rows
    unsigned short* __restrict__ outC, int gm_base) {
  __shared__ unsigned short pool[24576];      // Al | BlR | BlC (48KB)
  unsigned short* Al = pool;
  unsigned short* BlR = pool + 8192;
  unsigned short* BlC = pool + 16384;

  const int t = threadIdx.x;
  const int lane = t & 63;
  const int wv = t >> 6;
  const int wm = wv >> 1, wn = wv & 1;
  const int gm0 = gm_base + blockIdx.x * 128;
  const int n0 = blockIdx.y << 7;
  int logW, mbase;
  lvl_lookup(gm0, logW, mbase);
  const int logHW = 2 * logW;
  const int H = 1 << logW, W = H;
  const int HWm1 = (1 << logHW) - 1, Wm1 = W - 1;

  const int rsl = lane >> 3;
  const int chk = lane & 7;
  int hj[4], wj[4];
  const unsigned short* aptr[4];
  const unsigned short* bptrR[4];
  const unsigned short* bptrC[4];
  unsigned short* aldst[4];
  unsigned short* bldstR[4];
  unsigned short* bldstC[4];
#pragma unroll
  for (int i = 0; i < 4; ++i) {
    int slot = (wv << 2) + i;
    int gm = gm0 + (slot << 3) + rsl;
    int lm = gm - mbase;
    int hw = lm & HWm1;
    hj[i] = hw >> logW;
    wj[i] = hw & Wm1;
    aptr[i] = xin + ((size_t)gm << 8) + (chk << 3);
    int br = n0 + (slot << 3) + rsl;
    bptrR[i] = wtR + ((size_t)br << 8) + (chk << 3);
    bptrC[i] = wtC + ((size_t)br << 8) + (chk << 3);
    aldst[i] = Al + (slot << 9);
    bldstR[i] = BlR + (slot << 9);
    bldstC[i] = BlC + (slot << 9);
  }

  f32x4 accR[4][4], accC[4][4];
#pragma unroll
  for (int i = 0; i < 4; ++i)
#pragma unroll
    for (int j = 0; j < 4; ++j) {
      accR[i][j] = (f32x4){0.f, 0.f, 0.f, 0.f};
      accC[i][j] = (f32x4){0.f, 0.f, 0.f, 0.f};
    }

  const int arow = (wm << 6) + (lane & 15);
  const int brow = (wn << 6) + (lane & 15);
  const int kb = ((lane >> 4) << 4);

#pragma unroll 1
  for (int kstep = 0; kstep < 36; ++kstep) {
    const int kk = kstep >> 2;
    const int ic0 = (kstep & 3) << 6;
    const int dy = kk / 3 - 1, dxv = kk - (kk / 3) * 3 - 1;
    const int moff = (dy * W + dxv) << 8;
    __syncthreads();
#pragma unroll
    for (int i = 0; i < 4; ++i) {
      bool valid = ((unsigned)(hj[i] + dy) < (unsigned)H) &
                   ((unsigned)(wj[i] + dxv) < (unsigned)W);
      const unsigned short* g = valid ? (aptr[i] + moff + ic0) : zp;
      gload_lds16(g, aldst[i]);
    }
    const size_t bo = ((size_t)kk << 16) + ic0;
#pragma unroll
    for (int i = 0; i < 4; ++i) gload_lds16(bptrR[i] + bo, bldstR[i]);
#pragma unroll
    for (int i = 0; i < 4; ++i) gload_lds16(bptrC[i] + bo, bldstC[i]);
    __syncthreads();
#pragma unroll
    for (int ks = 0; ks < 2; ++ks) {
      f16x8 a[4], bR[4], bC[4];
#pragma unroll
      for (int mf = 0; mf < 4; ++mf)
        a[mf] = *reinterpret_cast<const f16x8*>(
            (const char*)Al + ((arow + (mf << 4)) << 7) + kb + (ks << 6));
#pragma unroll
      for (int nf = 0; nf < 4; ++nf) {
        bR[nf] = *reinterpret_cast<const f16x8*>(
            (const char*)BlR + ((brow + (nf << 4)) << 7) + kb + (ks << 6));
        bC[nf] = *reinterpret_cast<const f16x8*>(
            (const char*)BlC + ((brow + (nf << 4)) << 7) + kb + (ks << 6));
      }
#pragma unroll
      for (int mf = 0; mf < 4; ++mf)
#pragma unroll
        for (int nf = 0; nf < 4; ++nf) {
          accR[mf][nf] = __builtin_amdgcn_mfma_f32_16x16x32_f16(
              a[mf], bR[nf], accR[mf][nf], 0, 0, 0);
          accC[mf][nf] = __builtin_amdgcn_mfma_f32_16x16x32_f16(
              a[mf], bC[nf], accC[mf][nf], 0, 0, 0);
        }
    }
  }

  // ---- vectorized epilogue: acc -> LDS (f16, bias+relu) -> 16B stores
  const int erow = t >> 1;   // 0..127
  const int ech = t & 1;     // 64-col half
  const unsigned short* esrc =
      pool + ((((erow >> 6) << 1) + ech) << 12) + ((erow & 63) << 6);
  unsigned short* ep = pool + (wv << 12);
  const int eg = (lane >> 4) << 2;
  const int el = lane & 15;
  const int lrow0 = gm0 - gm_base;

  __syncthreads();
#pragma unroll
  for (int nf = 0; nf < 4; ++nf) {
    float bi = biasR[n0 + (wn << 6) + (nf << 4) + el];
#pragma unroll
    for (int mf = 0; mf < 4; ++mf)
#pragma unroll
      for (int r = 0; r < 4; ++r)
        ep[((mf << 4) + eg + r) * 64 + (nf << 4) + el] =
            f2h(fmaxf(accR[mf][nf][r] + bi, 0.0f));
  }
  __syncthreads();
  {
    unsigned short* edst =
        outR + ((size_t)(lrow0 + erow) << 8) + n0 + (ech << 6);
#pragma unroll
    for (int q = 0; q < 8; ++q)
      reinterpret_cast<uint4*>(edst)[q] =
          reinterpret_cast<const uint4*>(esrc)[q];
  }
  __syncthreads();
#pragma unroll
  for (int nf = 0; nf < 4; ++nf) {
    float bi = biasC[n0 + (wn << 6) + (nf << 4) + el];
#pragma unroll
    for (int mf = 0; mf < 4; ++mf)
#pragma unroll
      for (int r = 0; r < 4; ++r)
        ep[((mf << 4) + eg + r) * 64 + (nf << 4) + el] =
            f2h(fmaxf(accC[mf][nf][r] + bi, 0.0f));
  }
  __syncthreads();
  {
    unsigned short* edst =
        outC + ((size_t)(lrow0 + erow) << 8) + n0 + (ech << 6);
#pragma unroll
    for (int q = 0; q < 8; ++q)
      reinterpret_cast<uint4*>(edst)[q] =
          reinterpret_cast<const uint4*>(esrc)[q];
  }
}

// ----------------------------- conv2: 128Mx256N block, wave tile 64x128
__global__ __launch_bounds__(256, 2) void conv2w(
    const unsigned short* __restrict__ xin,  // group-local rows
    const unsigned short* __restrict__ wt,
    const float* __restrict__ bias,
    const unsigned short* __restrict__ zp,
    unsigned short* __restrict__ yout,       // absolute rows
    int gm_base) {
  __shared__ unsigned short pool[24576];     // Al(8192) | Bl(16384)
  unsigned short* Al = pool;
  unsigned short* Bl = pool + 8192;

  const int t = threadIdx.x;
  const int lane = t & 63;
  const int wv = t >> 6;
  const int wm = wv >> 1, wn = wv & 1;
  const int gm0 = gm_base + blockIdx.x * 128;
  int logW, mbase;
  lvl_lookup(gm0, logW, mbase);
  const int logHW = 2 * logW;
  const int H = 1 << logW, W = H;
  const int HWm1 = (1 << logHW) - 1, Wm1 = W - 1;

  const int rsl = lane >> 3;
  const int chk = lane & 7;
  int hj[4], wj[4];
  const unsigned short* aptr[4];
  unsigned short* aldst[4];
#pragma unroll
  for (int i = 0; i < 4; ++i) {
    int slot = (wv << 2) + i;
    int gm = gm0 + (slot << 3) + rsl;
    int lm = gm - mbase;
    int hw = lm & HWm1;
    hj[i] = hw >> logW;
    wj[i] = hw & Wm1;
    aptr[i] = xin + ((size_t)(gm - gm_base) << 8) + (chk << 3);
    aldst[i] = Al + (slot << 9);
  }
  const unsigned short* bptr[8];
  unsigned short* bldst[8];
#pragma unroll
  for (int i = 0; i < 8; ++i) {
    int slot = (wv << 3) + i;
    int row = (slot << 3) + rsl;
    bptr[i] = wt + ((size_t)row << 8) + (chk << 3);
    bldst[i] = Bl + (slot << 9);
  }

  f32x4 acc[4][8];
#pragma unroll
  for (int i = 0; i < 4; ++i)
#pragma unroll
    for (int j = 0; j < 8; ++j) acc[i][j] = (f32x4){0.f, 0.f, 0.f, 0.f};

  const int arow = (wm << 6) + (lane & 15);
  const int brow = (wn << 7) + (lane & 15);
  const int kb = ((lane >> 4) << 4);

#pragma unroll 1
  for (int kstep = 0; kstep < 36; ++kstep) {
    const int kk = kstep >> 2;
    const int ic0 = (kstep & 3) << 6;
    const int dy = kk / 3 - 1, dxv = kk - (kk / 3) * 3 - 1;
    const int moff = (dy * W + dxv) << 8;
    __syncthreads();
#pragma unroll
    for (int i = 0; i < 4; ++i) {
      bool valid = ((unsigned)(hj[i] + dy) < (unsigned)H) &
                   ((unsigned)(wj[i] + dxv) < (unsigned)W);
      const unsigned short* g = valid ? (aptr[i] + moff + ic0) : zp;
      gload_lds16(g, aldst[i]);
    }
    const size_t bo = ((size_t)kk << 16) + ic0;
#pragma unroll
    for (int i = 0; i < 8; ++i) gload_lds16(bptr[i] + bo, bldst[i]);
    __syncthreads();
#pragma unroll
    for (int ks = 0; ks < 2; ++ks) {
      f16x8 a[4], b[8];
#pragma unroll
      for (int mf = 0; mf < 4; ++mf)
        a[mf] = *reinterpret_cast<const f16x8*>(
            (const char*)Al + ((arow + (mf << 4)) << 7) + kb + (ks << 6));
#pragma unroll
      for (int nf = 0; nf < 8; ++nf)
        b[nf] = *reinterpret_cast<const f16x8*>(
            (const char*)Bl + ((brow + (nf << 4)) << 7) + kb + (ks << 6));
#pragma unroll
      for (int mf = 0; mf < 4; ++mf)
#pragma unroll
        for (int nf = 0; nf < 8; ++nf)
          acc[mf][nf] = __builtin_amdgcn_mfma_f32_16x16x32_f16(
              a[mf], b[nf], acc[mf][nf], 0, 0, 0);
    }
  }

  // ---- vectorized epilogue, two 64-col halves (each 32KB in pool)
  const int erow = t >> 1;
  const int ech = t & 1;
  const unsigned short* esrc =
      pool + ((((erow >> 6) << 1) + ech) << 12) + ((erow & 63) << 6);
  unsigned short* ep = pool + (wv << 12);
  const int eg = (lane >> 4) << 2;
  const int el = lane & 15;

#pragma unroll
  for (int h = 0; h < 2; ++h) {
    __syncthreads();
#pragma unroll
    for (int q4 = 0; q4 < 4; ++q4) {
      int nf = (h << 2) + q4;
      float bi = bias[(wn << 7) + (nf << 4) + el];
#pragma unroll
      for (int mf = 0; mf < 4; ++mf)
#pragma unroll
        for (int r = 0; r < 4; ++r)
          ep[((mf << 4) + eg + r) * 64 + (q4 << 4) + el] =
              f2h(fmaxf(acc[mf][nf][r] + bi, 0.0f));
    }
    __syncthreads();
    unsigned short* edst =
        yout + ((size_t)(gm0 + erow) << 8) + (ech << 7) + (h << 6);
#pragma unroll
    for (int q = 0; q < 8; ++q)
      reinterpret_cast<uint4*>(edst)[q] =
          reinterpret_cast<const uint4*>(esrc)[q];
  }
}

// -------------------------------------------- bbox(20)+conf(4) head -> hbuf
__global__ __launch_bounds__(256) void head24_mfma(
    const unsigned short* __restrict__ t2,  // group-local rows
    const unsigned short* __restrict__ wh,
    const float* __restrict__ regb, const float* __restrict__ confb,
    float* __restrict__ hbuf) {             // group-local rows
  const int t = threadIdx.x, lane = t & 63, wv = t >> 6;
  const int rowb = blockIdx.x * 256 + wv * 64;
  const int kgrp = (lane >> 4) << 3;
  const int l15 = lane & 15;
  f32x4 acc[4][2];
#pragma unroll
  for (int i = 0; i < 4; ++i)
#pragma unroll
    for (int j = 0; j < 2; ++j) acc[i][j] = (f32x4){0.f, 0.f, 0.f, 0.f};
#pragma unroll
  for (int k0 = 0; k0 < 256; k0 += 32) {
    f16x8 a[4], b[2];
#pragma unroll
    for (int mf = 0; mf < 4; ++mf)
      a[mf] = *reinterpret_cast<const f16x8*>(
          t2 + (((size_t)(rowb + (mf << 4) + l15)) << 8) + k0 + kgrp);
#pragma unroll
    for (int nf = 0; nf < 2; ++nf)
      b[nf] = *reinterpret_cast<const f16x8*>(
          wh + (size_t)(((nf << 4) + l15) << 8) + k0 + kgrp);
#pragma unroll
    for (int mf = 0; mf < 4; ++mf)
#pragma unroll
      for (int nf = 0; nf < 2; ++nf)
        acc[mf][nf] = __builtin_amdgcn_mfma_f32_16x16x32_f16(
            a[mf], b[nf], acc[mf][nf], 0, 0, 0);
  }
#pragma unroll
  for (int nf = 0; nf < 2; ++nf) {
    int c = (nf << 4) + l15;
    if (c < 24) {
      float bi = (c < 20) ? regb[c] : confb[c - 20];
#pragma unroll
      for (int mf = 0; mf < 4; ++mf)
#pragma unroll
        for (int r = 0; r < 4; ++r) {
          int m = rowb + (mf << 4) + ((lane >> 4) << 2) + r;
          hbuf[(size_t)m * 24 + c] = acc[mf][nf][r] + bi;
        }
    }
  }
}

// ------------------------------------------- cls head + sigmoid*sigmoid out
__global__ __launch_bounds__(256) void cls_scores(
    const unsigned short* __restrict__ t2,  // absolute rows (ws base)
    const unsigned short* __restrict__ wcw,
    const float* __restrict__ clsb,
    const float* __restrict__ hbuf,         // absolute rows
    float* __restrict__ outs, int gm_base) {
  const int t = threadIdx.x, lane = t & 63, wv = t >> 6;
  const int gm0 = gm_base + blockIdx.x * 256;
  int logW, mbase, lvl_off;
  if (gm0 < 131072) { logW = 7; mbase = 0; lvl_off = 0; }
  else if (gm0 < 163840) { logW = 6; mbase = 131072; lvl_off = 65536; }
  else if (gm0 < 172032) { logW = 5; mbase = 163840; lvl_off = 81920; }
  else if (gm0 < 174080) { logW = 4; mbase = 172032; lvl_off = 86016; }
  else { logW = 3; mbase = 174080; lvl_off = 87040; }
  const int logHW = 2 * logW, HWm1 = (1 << logHW) - 1;
  const int rowb = gm0 + wv * 64;
  const int kgrp = (lane >> 4) << 3;
  const int l15 = lane & 15;
  f32x4 acc[4][4];
#pragma unroll
  for (int i = 0; i < 4; ++i)
#pragma unroll
    for (int j = 0; j < 4; ++j) acc[i][j] = (f32x4){0.f, 0.f, 0.f, 0.f};
#pragma unroll
  for (int k0 = 0; k0 < 256; k0 += 32) {
    f16x8 a[4], b[4];
#pragma unroll
    for (int mf = 0; mf < 4; ++mf)
      a[mf] = *reinterpret_cast<const f16x8*>(
          t2 + (((size_t)(rowb + (mf << 4) + l15)) << 8) + k0 + kgrp);
#pragma unroll
    for (int nf = 0; nf < 4; ++nf)
      b[nf] = *reinterpret_cast<const f16x8*>(
          wcw + (size_t)(((nf << 4) + l15) << 8) + k0 + kgrp);
#pragma unroll
    for (int mf = 0; mf < 4; ++mf)
#pragma unroll
      for (int nf = 0; nf < 4; ++nf)
        acc[mf][nf] = __builtin_amdgcn_mfma_f32_16x16x32_f16(
            a[mf], b[nf], acc[mf][nf], 0, 0, 0);
  }
#pragma unroll
  for (int nf = 0; nf < 4; ++nf) {
    int c = (nf << 4) + l15;
    if (c < 60) {
      int ai = c / 15, ci = c - ai * 15;
      float bi = clsb[c];
#pragma unroll
      for (int mf = 0; mf < 4; ++mf)
#pragma unroll
        for (int r = 0; r < 4; ++r) {
          int m = rowb + (mf << 4) + ((lane >> 4) << 2) + r;
          float logit = acc[mf][nf][r] + bi;
          float conf = hbuf[(size_t)m * 24 + 20 + ai];
          float sc = sigmf(logit) * sigmf(conf);
          int lm = m - mbase;
          int b = lm >> logHW;
          int hw = lm & HWm1;
          int loc = lvl_off + (hw << 2) + ai;
          outs[(size_t)b * 1309440 + (size_t)loc * 15 + ci] = sc;
        }
    }
  }
}

// ------------------------------------------------- rbox decode, all levels
__global__ __launch_bounds__(256) void decode_all(
    const float* __restrict__ hbuf, float* __restrict__ outb) {
  int tid = blockIdx.x * 256 + threadIdx.x;
  if (tid >= 174592 * 4) return;
  int m = tid >> 2, a = tid & 3;
  int logW, mbase, lvl_off;
  float stride;
  if (m < 131072) { logW = 7; mbase = 0; lvl_off = 0; stride = 8.f; }
  else if (m < 163840) { logW = 6; mbase = 131072; lvl_off = 65536; stride = 16.f; }
  else if (m < 172032) { logW = 5; mbase = 163840; lvl_off = 81920; stride = 32.f; }
  else if (m < 174080) { logW = 4; mbase = 172032; lvl_off = 86016; stride = 64.f; }
  else { logW = 3; mbase = 174080; lvl_off = 87040; stride = 128.f; }
  const int logHW = 2 * logW;
  const float ANG[4] = {-0.39269908169872414f, 0.39269908169872414f,
                        1.1780972450961724f, 1.9634954084936207f};
  const float* d = hbuf + (size_t)m * 24 + a * 5;
  float dx = d[0], dy = d[1], dw = d[2], dh = d[3], da = d[4];
  int lm = m - mbase;
  int b = lm >> logHW, hw = lm & ((1 << logHW) - 1);
  int h = hw >> logW, w = hw & ((1 << logW) - 1);
  float ctr = 0.5f * (stride - 1.0f);
  float rx = w * stride + ctr, ry = h * stride + ctr;
  float rw = stride * 1.6329931618554521f;  // 4/sqrt(6)
  float rh = stride * 9.7979589711327124f;  // 4*sqrt(6)
  const float MR = 13.815510557964274f;     // |log(1e-6)|
  dw = fminf(fmaxf(dw, -MR), MR);
  dh = fminf(fmaxf(dh, -MR), MR);
  float gx = dx * rw + rx;
  float gy = dy * rh + ry;
  float gw = rw * expf(dw);
  float gh = rh * expf(dh);
  float v = da + ANG[a] + 0.7853981633974483f;
  float r = fmodf(v, 3.14159265358979323846f);
  if (r < 0.0f) r += 3.14159265358979323846f;
  float ga = r - 0.7853981633974483f;
  int loc = lvl_off + (hw << 2) + a;
  size_t base = (size_t)b * 436480 + (size_t)loc * 5;
  outb[base + 0] = gx;
  outb[base + 1] = gy;
  outb[base + 2] = gw;
  outb[base + 3] = gh;
  outb[base + 4] = ga;
}

// ============================================================================
extern "C" void kernel_launch(void* const* d_in, const int* in_sizes, int n_in,
                              void* d_out, int out_size, void* d_ws,
                              size_t ws_size, hipStream_t stream) {
  const float* feats[5];
  for (int i = 0; i < 5; ++i) feats[i] = (const float*)d_in[i];
  const float* reg_w0 = (const float*)d_in[5];
  const float* reg_b0 = (const float*)d_in[6];
  const float* reg_w1 = (const float*)d_in[7];
  const float* reg_b1 = (const float*)d_in[8];
  const float* cls_w0 = (const float*)d_in[9];
  const float* cls_b0 = (const float*)d_in[10];
  const float* cls_w1 = (const float*)d_in[11];
  const float* cls_b1 = (const float*)d_in[12];
  const float* reg_head_w = (const float*)d_in[13];
  const float* reg_head_b = (const float*)d_in[14];
  const float* cls_head_w = (const float*)d_in[15];
  const float* cls_head_b = (const float*)d_in[16];
  const float* conf_w = (const float*)d_in[17];
  const float* conf_b = (const float*)d_in[18];

  unsigned short* ws = (unsigned short*)d_ws;
  unsigned short* t1r = ws + 44695552ull;
  unsigned short* t1c = ws + 78249984ull;
  unsigned short* wt4 = ws + 111804416ull;
  unsigned short* wh = ws + 114163712ull;
  unsigned short* wc = ws + 114171904ull;
  unsigned short* zp = ws + 114188288ull;
  float* hbuf_all = (float*)((char*)d_ws + 228376704ull);

  prep_convw<<<9216, 256, 0, stream>>>(reg_w0, reg_w1, cls_w0, cls_w1, wt4);
  prep_small<<<97, 256, 0, stream>>>(cls_head_w, reg_head_w, conf_w, wc, wh,
                                     zp);
  to_nhwc_all<<<2728, 256, 0, stream>>>(feats[0], feats[1], feats[2], feats[3],
                                        feats[4], ws);

  float* scores = (float*)d_out;
  float* boxes = (float*)d_out + SCORES_TOTAL;

  // two groups: L0 alone (rows 0..131071), L1-4 merged (131072..174591)
  static const int gbase[2] = {0, 131072};
  static const int gM[2] = {131072, 43520};
  for (int g = 0; g < 2; ++g) {
    const int base = gbase[g];
    const int M = gM[g];
    const unsigned short* xg = ws;  // absolute rows inside kernels
    conv1f<<<dim3(M / 128, 2), 256, 0, stream>>>(
        xg, wt4 + 0ull * 589824, wt4 + 2ull * 589824, reg_b0, cls_b0, zp, t1r,
        t1c, base);
    conv2w<<<M / 128, 256, 0, stream>>>(t1r, wt4 + 1ull * 589824, reg_b1, zp,
                                        ws, base);
    head24_mfma<<<M / 256, 256, 0, stream>>>(
        ws + ((size_t)base << 8), wh, reg_head_b, conf_b,
        hbuf_all + (size_t)base * 24);
    conv2w<<<M / 128, 256, 0, stream>>>(t1c, wt4 + 3ull * 589824, cls_b1, zp,
                                        ws, base);
    cls_scores<<<M / 256, 256, 0, stream>>>(ws, wc, cls_head_b, hbuf_all,
                                            scores, base);
  }
  decode_all<<<(174592 * 4 + 255) / 256, 256, 0, stream>>>(hbuf_all, boxes);
}

// Round 8
// 1176.599 us; speedup vs baseline: 1.7735x; 1.0908x over previous
//
#include <hip/hip_runtime.h>

// ============================================================================
// RetinaNetHead (S2ANet-style rotated head), MI355X gfx950.
// R8: conv kernels rebuilt on the T3 "minimum 2-phase" pipeline:
//   - BK=32 phases (72/conv), double-buffered LDS (48KB total, occupancy kept)
//   - stage(t+1) issued BEFORE compute(t); ONE barrier per phase
//   - XOR bank-conflict swizzle (rule #21: linear gload_lds dest, inverse-XOR
//     per-lane SOURCE chunk, XOR on ds_read chunk): chunk ^= (row>>1)&3
//     R7 measured conflict cycles ~= 36% of conv runtime (9.07e7/dispatch).
// Rest identical to R7 (vectorized LDS epilogue, merged dispatches).
// fp32 accum; logits/decode fp32.
//
// Level geometry: rows gm 0..174591; cum={0,131072,163840,172032,174080,174592}
// Workspace (ushort units), same footprint (~245.1MB):
//   [0) feats NHWC fp16 (reused as t2) | [44,695,552) t1r | [78,249,984) t1c
//   [111,804,416) conv w 4x[9][256][256] | [114,163,712) wh | [114,171,904) wc
//   [114,188,288) zp | byte 228,376,704: hbuf fp32 [174592][24]
// ============================================================================

typedef __attribute__((ext_vector_type(8))) _Float16 f16x8;
typedef __attribute__((ext_vector_type(4))) float f32x4;

#define SCORES_TOTAL 10475520ull  // 8*87296*15

__device__ __forceinline__ unsigned short f2h(float f) {
  union { _Float16 h; unsigned short u; } x;
  x.h = (_Float16)f;
  return x.u;
}

__device__ __forceinline__ float sigmf(float x) {
  return 1.0f / (1.0f + expf(-x));
}

__device__ __forceinline__ void gload_lds16(const unsigned short* g,
                                            unsigned short* l) {
  __builtin_amdgcn_global_load_lds(
      (const __attribute__((address_space(1))) unsigned int*)g,
      (__attribute__((address_space(3))) unsigned int*)l, 16, 0, 0);
}

__device__ __forceinline__ void lvl_lookup(int gm, int& logW, int& mbase) {
  if (gm < 131072) { logW = 7; mbase = 0; }
  else if (gm < 163840) { logW = 6; mbase = 131072; }
  else if (gm < 172032) { logW = 5; mbase = 163840; }
  else if (gm < 174080) { logW = 4; mbase = 172032; }
  else { logW = 3; mbase = 174080; }
}

// ---------------------------------------------------------------- weight prep
__global__ __launch_bounds__(256) void prep_convw(
    const float* __restrict__ w0, const float* __restrict__ w1,
    const float* __restrict__ w2, const float* __restrict__ w3,
    unsigned short* __restrict__ wtout) {
  int g = blockIdx.x * 256 + threadIdx.x;  // < 4*589824
  int q = g >> 16;
  int wsel = q / 9;
  int kk = q - wsel * 9;
  int r = g & 65535;
  int oc = r >> 8, ic = r & 255;
  const float* src = (wsel == 0) ? w0 : (wsel == 1) ? w1 : (wsel == 2) ? w2 : w3;
  float v = src[(size_t)(oc * 256 + ic) * 9 + kk];
  wtout[(size_t)wsel * 589824 + (size_t)((kk << 8) + oc) * 256 + ic] = f2h(v);
}

__global__ __launch_bounds__(256) void prep_small(
    const float* __restrict__ clsh, const float* __restrict__ regh,
    const float* __restrict__ confw,
    unsigned short* __restrict__ wc, unsigned short* __restrict__ wh,
    unsigned short* __restrict__ zp) {
  int g = blockIdx.x * 256 + threadIdx.x;
  if (g < 16384) {
    int row = g >> 8, ic = g & 255;
    float v = (row < 60) ? clsh[row * 256 + ic] : 0.0f;
    wc[g] = f2h(v);
  } else if (g < 24576) {
    int gg = g - 16384;
    int row = gg >> 8, ic = gg & 255;
    float v = 0.0f;
    if (row < 20) v = regh[row * 256 + ic];
    else if (row < 24) v = confw[(row - 20) * 256 + ic];
    wh[gg] = f2h(v);
  } else if (g < 24640) {
    zp[g - 24576] = 0;
  }
}

// ------------------------------- NCHW fp32 -> NHWC fp16, all levels merged
__global__ __launch_bounds__(256) void to_nhwc_all(
    const float* __restrict__ f0, const float* __restrict__ f1,
    const float* __restrict__ f2, const float* __restrict__ f3,
    const float* __restrict__ f4, unsigned short* __restrict__ out) {
  __shared__ unsigned short L[64][258];
  const int t = threadIdx.x;
  const int gm0 = blockIdx.x * 64;
  int logW, mbase;
  const float* in;
  if (gm0 < 131072) { logW = 7; mbase = 0; in = f0; }
  else if (gm0 < 163840) { logW = 6; mbase = 131072; in = f1; }
  else if (gm0 < 172032) { logW = 5; mbase = 163840; in = f2; }
  else if (gm0 < 174080) { logW = 4; mbase = 172032; in = f3; }
  else { logW = 3; mbase = 174080; in = f4; }
  const int logHW = 2 * logW;
  const int HW = 1 << logHW;
  const int lm0 = gm0 - mbase;
  const int b = lm0 >> logHW;
  const int hw0 = lm0 & (HW - 1);
#pragma unroll
  for (int it = 0; it < 16; ++it) {
    int c = it * 16 + (t >> 4);
    int j4 = (t & 15) * 4;
    float4 v = *reinterpret_cast<const float4*>(
        in + (size_t)(b * 256 + c) * HW + hw0 + j4);
    L[j4 + 0][c] = f2h(v.x);
    L[j4 + 1][c] = f2h(v.y);
    L[j4 + 2][c] = f2h(v.z);
    L[j4 + 3][c] = f2h(v.w);
  }
  __syncthreads();
#pragma unroll
  for (int it = 0; it < 16; ++it) {
    int j = it * 4 + (t >> 6);
    int c4 = (t & 63) * 4;
    unsigned v0 = (unsigned)L[j][c4 + 0] | ((unsigned)L[j][c4 + 1] << 16);
    unsigned v1 = (unsigned)L[j][c4 + 2] | ((unsigned)L[j][c4 + 3] << 16);
    uint2 v = make_uint2(v0, v1);
    *reinterpret_cast<uint2*>(out + ((size_t)(gm0 + j) << 8) + c4) = v;
  }
}

// --------------------------- conv1 both towers fused: 128Mx128N, BK32 dbuf
__global__ __launch_bounds__(256, 2) void conv1f(
    const unsigned short* __restrict__ xin,   // absolute rows [gm][256]
    const unsigned short* __restrict__ wtR,
    const unsigned short* __restrict__ wtC,
    const float* __restrict__ biasR, const float* __restrict__ biasC,
    const unsigned short* __restrict__ zp,
    unsigned short* __restrict__ outR,        // group-local rows
    unsigned short* __restrict__ outC, int gm_base) {
  __shared__ unsigned short pool[24576];      // A 2x4096 | BR 2x4096 | BC 2x4096
  const int t = threadIdx.x;
  const int lane = t & 63;
  const int wv = t >> 6;
  const int wm = wv >> 1, wn = wv & 1;
  const int gm0 = gm_base + blockIdx.x * 128;
  const int n0 = blockIdx.y << 7;
  int logW, mbase;
  lvl_lookup(gm0, logW, mbase);
  const int logHW = 2 * logW;
  const int H = 1 << logW, W = H;
  const int HWm1 = (1 << logHW) - 1, Wm1 = W - 1;

  // staging coords: per wave 2 instrs each for A/BR/BC; rows wv*32+j*16+srow
  const int srow = lane >> 2;                               // 0..15
  const int schk = (((lane & 3) ^ ((lane >> 3) & 3)) << 3); // swizzled src chunk
  int hjj[2], wjj[2];
  const unsigned short* aptrj[2];
  const unsigned short* bRj[2];
  const unsigned short* bCj[2];
  const int sldrow = (wv << 5);  // LDS row base for this wave's staging
#pragma unroll
  for (int j = 0; j < 2; ++j) {
    int gm = gm0 + sldrow + (j << 4) + srow;
    int lm = gm - mbase;
    int hw = lm & HWm1;
    hjj[j] = hw >> logW;
    wjj[j] = hw & Wm1;
    aptrj[j] = xin + ((size_t)gm << 8) + schk;
    int br = n0 + sldrow + (j << 4) + srow;
    bRj[j] = wtR + ((size_t)br << 8) + schk;
    bCj[j] = wtC + ((size_t)br << 8) + schk;
  }

  f32x4 accR[4][4], accC[4][4];
#pragma unroll
  for (int i = 0; i < 4; ++i)
#pragma unroll
    for (int j = 0; j < 4; ++j) {
      accR[i][j] = (f32x4){0.f, 0.f, 0.f, 0.f};
      accC[i][j] = (f32x4){0.f, 0.f, 0.f, 0.f};
    }

  const int arow = (wm << 6) + (lane & 15);
  const int brow = (wn << 6) + (lane & 15);
  const int sxor = ((lane & 15) >> 1) & 3;
  const int achk = (((lane >> 4) ^ sxor) << 3);  // swizzled read chunk (elems)

  // ---- prologue: stage phase 0 into buf 0
  {
    const int moff = (-W - 1) << 8;  // kk=0: dy=-1,dx=-1
#pragma unroll
    for (int j = 0; j < 2; ++j) {
      bool valid = (hjj[j] > 0) & (wjj[j] > 0);
      const unsigned short* g = valid ? (aptrj[j] + moff) : zp;
      gload_lds16(g, pool + ((sldrow + (j << 4)) << 5));
    }
#pragma unroll
    for (int j = 0; j < 2; ++j) {
      gload_lds16(bRj[j], pool + 8192 + ((sldrow + (j << 4)) << 5));
      gload_lds16(bCj[j], pool + 16384 + ((sldrow + (j << 4)) << 5));
    }
  }
  __syncthreads();

  int cur = 0;
#pragma unroll 1
  for (int ph = 0; ph < 72; ++ph) {
    if (ph < 71) {  // stage phase ph+1 into buf cur^1
      const int p = ph + 1;
      const int kk = p >> 3;
      const int k3 = kk / 3;
      const int dy = k3 - 1, dxv = kk - k3 * 3 - 1;
      const int moff = ((dy << logW) + dxv) << 8;
      const int ic0 = (p & 7) << 5;
      const int nb = (cur ^ 1) << 12;  // 4096 elems per buffer
      const int bko = (kk << 16) + ic0;
#pragma unroll
      for (int j = 0; j < 2; ++j) {
        bool valid = ((unsigned)(hjj[j] + dy) < (unsigned)H) &
                     ((unsigned)(wjj[j] + dxv) < (unsigned)W);
        const unsigned short* g = valid ? (aptrj[j] + moff + ic0) : zp;
        gload_lds16(g, pool + nb + ((sldrow + (j << 4)) << 5));
      }
#pragma unroll
      for (int j = 0; j < 2; ++j) {
        gload_lds16(bRj[j] + bko, pool + 8192 + nb + ((sldrow + (j << 4)) << 5));
        gload_lds16(bCj[j] + bko, pool + 16384 + nb + ((sldrow + (j << 4)) << 5));
      }
    }
    // compute from buf cur
    const int cb = cur << 12;
    f16x8 a[4], bR[4], bC[4];
#pragma unroll
    for (int mf = 0; mf < 4; ++mf)
      a[mf] = *reinterpret_cast<const f16x8*>(
          pool + cb + ((arow + (mf << 4)) << 5) + achk);
#pragma unroll
    for (int nf = 0; nf < 4; ++nf) {
      bR[nf] = *reinterpret_cast<const f16x8*>(
          pool + 8192 + cb + ((brow + (nf << 4)) << 5) + achk);
      bC[nf] = *reinterpret_cast<const f16x8*>(
          pool + 16384 + cb + ((brow + (nf << 4)) << 5) + achk);
    }
#pragma unroll
    for (int mf = 0; mf < 4; ++mf)
#pragma unroll
      for (int nf = 0; nf < 4; ++nf) {
        accR[mf][nf] = __builtin_amdgcn_mfma_f32_16x16x32_f16(
            a[mf], bR[nf], accR[mf][nf], 0, 0, 0);
        accC[mf][nf] = __builtin_amdgcn_mfma_f32_16x16x32_f16(
            a[mf], bC[nf], accC[mf][nf], 0, 0, 0);
      }
    __syncthreads();
    cur ^= 1;
  }

  // ---- vectorized epilogue (R7): acc -> LDS f16 -> 16B stores
  const int erow = t >> 1;
  const int ech = t & 1;
  const unsigned short* esrc =
      pool + ((((erow >> 6) << 1) + ech) << 12) + ((erow & 63) << 6);
  unsigned short* ep = pool + (wv << 12);
  const int eg = (lane >> 4) << 2;
  const int el = lane & 15;
  const int lrow0 = gm0 - gm_base;

#pragma unroll
  for (int nf = 0; nf < 4; ++nf) {
    float bi = biasR[n0 + (wn << 6) + (nf << 4) + el];
#pragma unroll
    for (int mf = 0; mf < 4; ++mf)
#pragma unroll
      for (int r = 0; r < 4; ++r)
        ep[((mf << 4) + eg + r) * 64 + (nf << 4) + el] =
            f2h(fmaxf(accR[mf][nf][r] + bi, 0.0f));
  }
  __syncthreads();
  {
    unsigned short* edst =
        outR + ((size_t)(lrow0 + erow) << 8) + n0 + (ech << 6);
#pragma unroll
    for (int q = 0; q < 8; ++q)
      reinterpret_cast<uint4*>(edst)[q] =
          reinterpret_cast<const uint4*>(esrc)[q];
  }
  __syncthreads();
#pragma unroll
  for (int nf = 0; nf < 4; ++nf) {
    float bi = biasC[n0 + (wn << 6) + (nf << 4) + el];
#pragma unroll
    for (int mf = 0; mf < 4; ++mf)
#pragma unroll
      for (int r = 0; r < 4; ++r)
        ep[((mf << 4) + eg + r) * 64 + (nf << 4) + el] =
            f2h(fmaxf(accC[mf][nf][r] + bi, 0.0f));
  }
  __syncthreads();
  {
    unsigned short* edst =
        outC + ((size_t)(lrow0 + erow) << 8) + n0 + (ech << 6);
#pragma unroll
    for (int q = 0; q < 8; ++q)
      reinterpret_cast<uint4*>(edst)[q] =
          reinterpret_cast<const uint4*>(esrc)[q];
  }
}

// ----------------------------- conv2: 128Mx256N block, BK32 dbuf
__global__ __launch_bounds__(256, 2) void conv2w(
    const unsigned short* __restrict__ xin,  // group-local rows
    const unsigned short* __restrict__ wt,
    const float* __restrict__ bias,
    const unsigned short* __restrict__ zp,
    unsigned short* __restrict__ yout,       // absolute rows
    int gm_base) {
  __shared__ unsigned short pool[24576];     // A 2x4096 | B 2x8192
  const int t = threadIdx.x;
  const int lane = t & 63;
  const int wv = t >> 6;
  const int wm = wv >> 1, wn = wv & 1;       // wave tile 64M x 128N
  const int gm0 = gm_base + blockIdx.x * 128;
  int logW, mbase;
  lvl_lookup(gm0, logW, mbase);
  const int logHW = 2 * logW;
  const int H = 1 << logW, W = H;
  const int HWm1 = (1 << logHW) - 1, Wm1 = W - 1;

  const int srow = lane >> 2;
  const int schk = (((lane & 3) ^ ((lane >> 3) & 3)) << 3);
  int hjj[2], wjj[2];
  const unsigned short* aptrj[2];
  const int sldrow = (wv << 5);
#pragma unroll
  for (int j = 0; j < 2; ++j) {
    int gm = gm0 + sldrow + (j << 4) + srow;
    int lm = gm - mbase;
    int hw = lm & HWm1;
    hjj[j] = hw >> logW;
    wjj[j] = hw & Wm1;
    aptrj[j] = xin + ((size_t)(gm - gm_base) << 8) + schk;
  }
  const unsigned short* bpj[4];
#pragma unroll
  for (int j = 0; j < 4; ++j) {
    int row = (wv << 6) + (j << 4) + srow;   // 0..255
    bpj[j] = wt + ((size_t)row << 8) + schk;
  }

  f32x4 acc[4][8];
#pragma unroll
  for (int i = 0; i < 4; ++i)
#pragma unroll
    for (int j = 0; j < 8; ++j) acc[i][j] = (f32x4){0.f, 0.f, 0.f, 0.f};

  const int arow = (wm << 6) + (lane & 15);
  const int brow = (wn << 7) + (lane & 15);
  const int sxor = ((lane & 15) >> 1) & 3;
  const int achk = (((lane >> 4) ^ sxor) << 3);

  // prologue: stage phase 0 (kk=0: dy=-1,dx=-1) into buf 0
  {
    const int moff = (-W - 1) << 8;
#pragma unroll
    for (int j = 0; j < 2; ++j) {
      bool valid = (hjj[j] > 0) & (wjj[j] > 0);
      const unsigned short* g = valid ? (aptrj[j] + moff) : zp;
      gload_lds16(g, pool + ((sldrow + (j << 4)) << 5));
    }
#pragma unroll
    for (int j = 0; j < 4; ++j)
      gload_lds16(bpj[j], pool + 8192 + (((wv << 6) + (j << 4)) << 5));
  }
  __syncthreads();

  int cur = 0;
#pragma unroll 1
  for (int ph = 0; ph < 72; ++ph) {
    if (ph < 71) {
      const int p = ph + 1;
      const int kk = p >> 3;
      const int k3 = kk / 3;
      const int dy = k3 - 1, dxv = kk - k3 * 3 - 1;
      const int moff = ((dy << logW) + dxv) << 8;
      const int ic0 = (p & 7) << 5;
      const int bko = (kk << 16) + ic0;
#pragma unroll
      for (int j = 0; j < 2; ++j) {
        bool valid = ((unsigned)(hjj[j] + dy) < (unsigned)H) &
                     ((unsigned)(wjj[j] + dxv) < (unsigned)W);
        const unsigned short* g = valid ? (aptrj[j] + moff + ic0) : zp;
        gload_lds16(g, pool + ((cur ^ 1) << 12) + ((sldrow + (j << 4)) << 5));
      }
#pragma unroll
      for (int j = 0; j < 4; ++j)
        gload_lds16(bpj[j] + bko, pool + 8192 + ((cur ^ 1) << 13) +
                                      (((wv << 6) + (j << 4)) << 5));
    }
    const int cbA = cur << 12;
    const int cbB = cur << 13;
    f16x8 a[4], b[8];
#pragma unroll
    for (int mf = 0; mf < 4; ++mf)
      a[mf] = *reinterpret_cast<const f16x8*>(
          pool + cbA + ((arow + (mf << 4)) << 5) + achk);
#pragma unroll
    for (int nf = 0; nf < 8; ++nf)
      b[nf] = *reinterpret_cast<const f16x8*>(
          pool + 8192 + cbB + ((brow + (nf << 4)) << 5) + achk);
#pragma unroll
    for (int mf = 0; mf < 4; ++mf)
#pragma unroll
      for (int nf = 0; nf < 8; ++nf)
        acc[mf][nf] = __builtin_amdgcn_mfma_f32_16x16x32_f16(
            a[mf], b[nf], acc[mf][nf], 0, 0, 0);
    __syncthreads();
    cur ^= 1;
  }

  // ---- vectorized epilogue (R7), two 64-col halves
  const int erow = t >> 1;
  const int ech = t & 1;
  const unsigned short* esrc =
      pool + ((((erow >> 6) << 1) + ech) << 12) + ((erow & 63) << 6);
  unsigned short* ep = pool + (wv << 12);
  const int eg = (lane >> 4) << 2;
  const int el = lane & 15;

#pragma unroll
  for (int h = 0; h < 2; ++h) {
    __syncthreads();
#pragma unroll
    for (int q4 = 0; q4 < 4; ++q4) {
      int nf = (h << 2) + q4;
      float bi = bias[(wn << 7) + (nf << 4) + el];
#pragma unroll
      for (int mf = 0; mf < 4; ++mf)
#pragma unroll
        for (int r = 0; r < 4; ++r)
          ep[((mf << 4) + eg + r) * 64 + (q4 << 4) + el] =
              f2h(fmaxf(acc[mf][nf][r] + bi, 0.0f));
    }
    __syncthreads();
    unsigned short* edst =
        yout + ((size_t)(gm0 + erow) << 8) + (ech << 7) + (h << 6);
#pragma unroll
    for (int q = 0; q < 8; ++q)
      reinterpret_cast<uint4*>(edst)[q] =
          reinterpret_cast<const uint4*>(esrc)[q];
  }
}

// -------------------------------------------- bbox(20)+conf(4) head -> hbuf
__global__ __launch_bounds__(256) void head24_mfma(
    const unsigned short* __restrict__ t2,  // group-local rows
    const unsigned short* __restrict__ wh,
    const float* __restrict__ regb, const float* __restrict__ confb,
    float* __restrict__ hbuf) {             // group-local rows
  const int t = threadIdx.x, lane = t & 63, wv = t >> 6;
  const int rowb = blockIdx.x * 256 + wv * 64;
  const int kgrp = (lane >> 4) << 3;
  const int l15 = lane & 15;
  f32x4 acc[4][2];
#pragma unroll
  for (int i = 0; i < 4; ++i)
#pragma unroll
    for (int j = 0; j < 2; ++j) acc[i][j] = (f32x4){0.f, 0.f, 0.f, 0.f};
#pragma unroll
  for (int k0 = 0; k0 < 256; k0 += 32) {
    f16x8 a[4], b[2];
#pragma unroll
    for (int mf = 0; mf < 4; ++mf)
      a[mf] = *reinterpret_cast<const f16x8*>(
          t2 + (((size_t)(rowb + (mf << 4) + l15)) << 8) + k0 + kgrp);
#pragma unroll
    for (int nf = 0; nf < 2; ++nf)
      b[nf] = *reinterpret_cast<const f16x8*>(
          wh + (size_t)(((nf << 4) + l15) << 8) + k0 + kgrp);
#pragma unroll
    for (int mf = 0; mf < 4; ++mf)
#pragma unroll
      for (int nf = 0; nf < 2; ++nf)
        acc[mf][nf] = __builtin_amdgcn_mfma_f32_16x16x32_f16(
            a[mf], b[nf], acc[mf][nf], 0, 0, 0);
  }
#pragma unroll
  for (int nf = 0; nf < 2; ++nf) {
    int c = (nf << 4) + l15;
    if (c < 24) {
      float bi = (c < 20) ? regb[c] : confb[c - 20];
#pragma unroll
      for (int mf = 0; mf < 4; ++mf)
#pragma unroll
        for (int r = 0; r < 4; ++r) {
          int m = rowb + (mf << 4) + ((lane >> 4) << 2) + r;
          hbuf[(size_t)m * 24 + c] = acc[mf][nf][r] + bi;
        }
    }
  }
}

// ------------------------------------------- cls head + sigmoid*sigmoid out
__global__ __launch_bounds__(256) void cls_scores(
    const unsigned short* __restrict__ t2,  // absolute rows (ws base)
    const unsigned short* __restrict__ wcw,
    const float* __restrict__ clsb,
    const float* __restrict__ hbuf,         // absolute rows
    float* __restrict__ outs, int gm_base) {
  const int t = threadIdx.x, lane = t & 63, wv = t >> 6;
  const int gm0 = gm_base + blockIdx.x * 256;
  int logW, mbase, lvl_off;
  if (gm0 < 131072) { logW = 7; mbase = 0; lvl_off = 0; }
  else if (gm0 < 163840) { logW = 6; mbase = 131072; lvl_off = 65536; }
  else if (gm0 < 172032) { logW = 5; mbase = 163840; lvl_off = 81920; }
  else if (gm0 < 174080) { logW = 4; mbase = 172032; lvl_off = 86016; }
  else { logW = 3; mbase = 174080; lvl_off = 87040; }
  const int logHW = 2 * logW, HWm1 = (1 << logHW) - 1;
  const int rowb = gm0 + wv * 64;
  const int kgrp = (lane >> 4) << 3;
  const int l15 = lane & 15;
  f32x4 acc[4][4];
#pragma unroll
  for (int i = 0; i < 4; ++i)
#pragma unroll
    for (int j = 0; j < 4; ++j) acc[i][j] = (f32x4){0.f, 0.f, 0.f, 0.f};
#pragma unroll
  for (int k0 = 0; k0 < 256; k0 += 32) {
    f16x8 a[4], b[4];
#pragma unroll
    for (int mf = 0; mf < 4; ++mf)
      a[mf] = *reinterpret_cast<const f16x8*>(
          t2 + (((size_t)(rowb + (mf << 4) + l15)) << 8) + k0 + kgrp);
#pragma unroll
    for (int nf = 0; nf < 4; ++nf)
      b[nf] = *reinterpret_cast<const f16x8*>(
          wcw + (size_t)(((nf << 4) + l15) << 8) + k0 + kgrp);
#pragma unroll
    for (int mf = 0; mf < 4; ++mf)
#pragma unroll
      for (int nf = 0; nf < 4; ++nf)
        acc[mf][nf] = __builtin_amdgcn_mfma_f32_16x16x32_f16(
            a[mf], b[nf], acc[mf][nf], 0, 0, 0);
  }
#pragma unroll
  for (int nf = 0; nf < 4; ++nf) {
    int c = (nf << 4) + l15;
    if (c < 60) {
      int ai = c / 15, ci = c - ai * 15;
      float bi = clsb[c];
#pragma unroll
      for (int mf = 0; mf < 4; ++mf)
#pragma unroll
        for (int r = 0; r < 4; ++r) {
          int m = rowb + (mf << 4) + ((lane >> 4) << 2) + r;
          float logit = acc[mf][nf][r] + bi;
          float conf = hbuf[(size_t)m * 24 + 20 + ai];
          float sc = sigmf(logit) * sigmf(conf);
          int lm = m - mbase;
          int b = lm >> logHW;
          int hw = lm & HWm1;
          int loc = lvl_off + (hw << 2) + ai;
          outs[(size_t)b * 1309440 + (size_t)loc * 15 + ci] = sc;
        }
    }
  }
}

// ------------------------------------------------- rbox decode, all levels
__global__ __launch_bounds__(256) void decode_all(
    const float* __restrict__ hbuf, float* __restrict__ outb) {
  int tid = blockIdx.x * 256 + threadIdx.x;
  if (tid >= 174592 * 4) return;
  int m = tid >> 2, a = tid & 3;
  int logW, mbase, lvl_off;
  float stride;
  if (m < 131072) { logW = 7; mbase = 0; lvl_off = 0; stride = 8.f; }
  else if (m < 163840) { logW = 6; mbase = 131072; lvl_off = 65536; stride = 16.f; }
  else if (m < 172032) { logW = 5; mbase = 163840; lvl_off = 81920; stride = 32.f; }
  else if (m < 174080) { logW = 4; mbase = 172032; lvl_off = 86016; stride = 64.f; }
  else { logW = 3; mbase = 174080; lvl_off = 87040; stride = 128.f; }
  const int logHW = 2 * logW;
  const float ANG[4] = {-0.39269908169872414f, 0.39269908169872414f,
                        1.1780972450961724f, 1.9634954084936207f};
  const float* d = hbuf + (size_t)m * 24 + a * 5;
  float dx = d[0], dy = d[1], dw = d[2], dh = d[3], da = d[4];
  int lm = m - mbase;
  int b = lm >> logHW, hw = lm & ((1 << logHW) - 1);
  int h = hw >> logW, w = hw & ((1 << logW) - 1);
  float ctr = 0.5f * (stride - 1.0f);
  float rx = w * stride + ctr, ry = h * stride + ctr;
  float rw = stride * 1.6329931618554521f;  // 4/sqrt(6)
  float rh = stride * 9.7979589711327124f;  // 4*sqrt(6)
  const float MR = 13.815510557964274f;     // |log(1e-6)|
  dw = fminf(fmaxf(dw, -MR), MR);
  dh = fminf(fmaxf(dh, -MR), MR);
  float gx = dx * rw + rx;
  float gy = dy * rh + ry;
  float gw = rw * expf(dw);
  float gh = rh * expf(dh);
  float v = da + ANG[a] + 0.7853981633974483f;
  float r = fmodf(v, 3.14159265358979323846f);
  if (r < 0.0f) r += 3.14159265358979323846f;
  float ga = r - 0.7853981633974483f;
  int loc = lvl_off + (hw << 2) + a;
  size_t base = (size_t)b * 436480 + (size_t)loc * 5;
  outb[base + 0] = gx;
  outb[base + 1] = gy;
  outb[base + 2] = gw;
  outb[base + 3] = gh;
  outb[base + 4] = ga;
}

// ============================================================================
extern "C" void kernel_launch(void* const* d_in, const int* in_sizes, int n_in,
                              void* d_out, int out_size, void* d_ws,
                              size_t ws_size, hipStream_t stream) {
  const float* feats[5];
  for (int i = 0; i < 5; ++i) feats[i] = (const float*)d_in[i];
  const float* reg_w0 = (const float*)d_in[5];
  const float* reg_b0 = (const float*)d_in[6];
  const float* reg_w1 = (const float*)d_in[7];
  const float* reg_b1 = (const float*)d_in[8];
  const float* cls_w0 = (const float*)d_in[9];
  const float* cls_b0 = (const float*)d_in[10];
  const float* cls_w1 = (const float*)d_in[11];
  const float* cls_b1 = (const float*)d_in[12];
  const float* reg_head_w = (const float*)d_in[13];
  const float* reg_head_b = (const float*)d_in[14];
  const float* cls_head_w = (const float*)d_in[15];
  const float* cls_head_b = (const float*)d_in[16];
  const float* conf_w = (const float*)d_in[17];
  const float* conf_b = (const float*)d_in[18];

  unsigned short* ws = (unsigned short*)d_ws;
  unsigned short* t1r = ws + 44695552ull;
  unsigned short* t1c = ws + 78249984ull;
  unsigned short* wt4 = ws + 111804416ull;
  unsigned short* wh = ws + 114163712ull;
  unsigned short* wc = ws + 114171904ull;
  unsigned short* zp = ws + 114188288ull;
  float* hbuf_all = (float*)((char*)d_ws + 228376704ull);

  prep_convw<<<9216, 256, 0, stream>>>(reg_w0, reg_w1, cls_w0, cls_w1, wt4);
  prep_small<<<97, 256, 0, stream>>>(cls_head_w, reg_head_w, conf_w, wc, wh,
                                     zp);
  to_nhwc_all<<<2728, 256, 0, stream>>>(feats[0], feats[1], feats[2], feats[3],
                                        feats[4], ws);

  float* scores = (float*)d_out;
  float* boxes = (float*)d_out + SCORES_TOTAL;

  static const int gbase[2] = {0, 131072};
  static const int gM[2] = {131072, 43520};
  for (int g = 0; g < 2; ++g) {
    const int base = gbase[g];
    const int M = gM[g];
    conv1f<<<dim3(M / 128, 2), 256, 0, stream>>>(
        ws, wt4 + 0ull * 589824, wt4 + 2ull * 589824, reg_b0, cls_b0, zp, t1r,
        t1c, base);
    conv2w<<<M / 128, 256, 0, stream>>>(t1r, wt4 + 1ull * 589824, reg_b1, zp,
                                        ws, base);
    head24_mfma<<<M / 256, 256, 0, stream>>>(
        ws + ((size_t)base << 8), wh, reg_head_b, conf_b,
        hbuf_all + (size_t)base * 24);
    conv2w<<<M / 128, 256, 0, stream>>>(t1c, wt4 + 3ull * 589824, cls_b1, zp,
                                        ws, base);
    cls_scores<<<M / 256, 256, 0, stream>>>(ws, wc, cls_head_b, hbuf_all,
                                            scores, base);
  }
  decode_all<<<(174592 * 4 + 255) / 256, 256, 0, stream>>>(hbuf_all, boxes);
}